// Round 8
// baseline (279.442 us; speedup 1.0000x reference)
//
#include <hip/hip_runtime.h>
#include <hip/hip_fp16.h>

#define N_NODES 50000
#define N_EDGES 800000
#define IN_CH 128
#define HID 64
#define OUT_CH 32
#define NBLK 196                 // ceil(50000/256)
#define PART_SZ 6250             // N_NODES / 8 (XCD dst partitions)
#define ZROW N_NODES             // all-zeros feature row (padding gathers)

union H4 { uint2 u; __half2 h[2]; };

// ---------------- histogram of dst -----------------------------------------
__global__ __launch_bounds__(256) void k_hist(const int* __restrict__ ei, int* cnt) {
    int e = blockIdx.x * 256 + threadIdx.x;
    if (e < N_EDGES) atomicAdd(&cnt[ei[N_EDGES + e]], 1);
}

// ---------------- single-kernel scan: block scan + atomic base -------------
// CSR row ranges land in arbitrary block order — fine, since agg uses
// end = row_start[w] + cnt[w]. Also computes dis, pads pk, zeros ZROW rows.
__global__ __launch_bounds__(256) void k_scan(const int* __restrict__ cnt, int* total,
                                              int* row_start, int* cur, float* dis,
                                              int* pk, unsigned* zA0, unsigned* zA1,
                                              unsigned* zB0, unsigned* zB1) {
    __shared__ int s[256];
    __shared__ int sbase;
    int t = threadIdx.x;
    int i = blockIdx.x * 256 + t;
    int v = cnt[i];                          // padded region zeroed by memset
    s[t] = v;
    __syncthreads();
    for (int off = 1; off < 256; off <<= 1) {
        int a = (t >= off) ? s[t - off] : 0;
        __syncthreads();
        s[t] += a;
        __syncthreads();
    }
    if (t == 255) sbase = atomicAdd(total, s[255]);
    __syncthreads();
    int excl = sbase + s[t] - v;
    if (i < N_NODES) {
        row_start[i] = excl;
        cur[i] = excl;
        dis[i] = rsqrtf((float)(v + 1));     // self-loop included
    }
    if (blockIdx.x == 0 && t < 16) {
        pk[N_EDGES + t] = ZROW;              // pad for 16-wide agg reads
        zA0[t] = 0u; zA1[t] = 0u; zB0[t] = 0u; zB1[t] = 0u;  // 32-half zero rows
    }
}

// ---------------- scatter edges, XCD-partitioned, src-only payload ---------
__global__ __launch_bounds__(256) void k_scatter(const int* __restrict__ ei,
                                                 int* cur, int* __restrict__ pk) {
    int part = blockIdx.x & 7;
    int e = (blockIdx.x >> 3) * 256 + threadIdx.x;
    if (e >= N_EDGES) return;
    int d = ei[N_EDGES + e];
    if (d / PART_SZ != part) return;
    int pos = atomicAdd(&cur[d], 1);
    pk[pos] = ei[e];
}

// ---------------- t1' = dis .* (x @ W1), 4x4 tiled, half lo/hi out ---------
__global__ __launch_bounds__(256) void k_mm1(const float* __restrict__ x,
                                             const float* __restrict__ W1,
                                             const float* __restrict__ dis,
                                             __half* __restrict__ t1lo,
                                             __half* __restrict__ t1hi) {
    __shared__ float4 ws[64 * 16];      // W half-tile [k][cq], 16 KB
    __shared__ float  xsT[64 * 64];     // x half-tile, transposed+swizzled, 16 KB
    int t = threadIdx.x;
    int n0 = blockIdx.x * 64;
    int lane = t & 63, wv_ = t >> 6;
    int ni = lane >> 2;                 // node-quad 0..15
    int cq = ((lane & 3) << 2) + wv_;   // channel-quad 0..15
    const float4* W4 = (const float4*)W1;
    const float4* x4 = (const float4*)x;
    float4 acc0 = {0,0,0,0}, acc1 = acc0, acc2 = acc0, acc3 = acc0;
#pragma unroll
    for (int kt = 0; kt < 2; ++kt) {
        __syncthreads();
#pragma unroll
        for (int i = 0; i < 4; ++i) {
            int L = i * 256 + t;
            ws[L] = W4[kt * 1024 + L];
            int n = L >> 4, q = L & 15;
            int ng = n0 + n; if (ng >= N_NODES) ng = N_NODES - 1;
            float4 v = x4[ng * 32 + kt * 16 + q];
            int fb = q * 256 + (((n >> 2) ^ q) << 2) + (n & 3);
            xsT[fb]       = v.x;
            xsT[fb + 64]  = v.y;
            xsT[fb + 128] = v.z;
            xsT[fb + 192] = v.w;
        }
        __syncthreads();
        const float4* xsT4 = (const float4*)xsT;
#pragma unroll 8
        for (int k = 0; k < 64; ++k) {
            float4 xv = xsT4[k * 16 + (ni ^ (k >> 2))];
            float4 wvv = ws[k * 16 + cq];
            acc0.x += xv.x * wvv.x; acc0.y += xv.x * wvv.y; acc0.z += xv.x * wvv.z; acc0.w += xv.x * wvv.w;
            acc1.x += xv.y * wvv.x; acc1.y += xv.y * wvv.y; acc1.z += xv.y * wvv.z; acc1.w += xv.y * wvv.w;
            acc2.x += xv.z * wvv.x; acc2.y += xv.z * wvv.y; acc2.z += xv.z * wvv.z; acc2.w += xv.z * wvv.w;
            acc3.x += xv.w * wvv.x; acc3.y += xv.w * wvv.y; acc3.z += xv.w * wvv.z; acc3.w += xv.w * wvv.w;
        }
    }
    int nb = n0 + 4 * ni;
    if (nb < N_NODES) {
        float d0 = dis[nb], d1 = dis[nb + 1], d2 = dis[nb + 2], d3 = dis[nb + 3];
        uint2* o2 = (cq < 8) ? (uint2*)t1lo : (uint2*)t1hi;   // 8 uint2/row halves
        int c8 = cq & 7;
        H4 v;
        v.h[0] = __floats2half2_rn(d0 * acc0.x, d0 * acc0.y);
        v.h[1] = __floats2half2_rn(d0 * acc0.z, d0 * acc0.w);
        o2[(nb + 0) * 8 + c8] = v.u;
        v.h[0] = __floats2half2_rn(d1 * acc1.x, d1 * acc1.y);
        v.h[1] = __floats2half2_rn(d1 * acc1.z, d1 * acc1.w);
        o2[(nb + 1) * 8 + c8] = v.u;
        v.h[0] = __floats2half2_rn(d2 * acc2.x, d2 * acc2.y);
        v.h[1] = __floats2half2_rn(d2 * acc2.z, d2 * acc2.w);
        o2[(nb + 2) * 8 + c8] = v.u;
        v.h[0] = __floats2half2_rn(d3 * acc3.x, d3 * acc3.y);
        v.h[1] = __floats2half2_rn(d3 * acc3.z, d3 * acc3.w);
        o2[(nb + 3) * 8 + c8] = v.u;
    }
}

// ---------------- half-channel aggregation: 16 edges per gather instr ------
// in/out are 32-channel half-buffers (64 B rows, 4 uint4). Gather working set
// = 3.2 MB -> fits per-XCD L2. Wave = 16 edge-groups x 4 ch-lanes.
// mode 1: out = half( dis[w] * relu(dis[w]*acc + bias32) )
// mode 0: out = half( dis[w] * acc )
__global__ __launch_bounds__(256) void k_aggh(const int* __restrict__ pk,
                                              const int* __restrict__ row_start,
                                              const int* __restrict__ cnt,
                                              const float* __restrict__ dis,
                                              const __half* __restrict__ in,
                                              const float* __restrict__ bias,
                                              __half* __restrict__ out,
                                              int apply_relu) {
    int w = (blockIdx.x * 256 + threadIdx.x) >> 6;
    if (w >= N_NODES) return;
    int lane = threadIdx.x & 63;
    int eg = lane >> 2, cs = lane & 3;
    int beg = row_start[w], end = beg + cnt[w];
    const uint4* __restrict__ inv = (const uint4*)in;    // 4 uint4 per row
    float acc[8] = {0,0,0,0,0,0,0,0};
#pragma unroll 2
    for (int base = beg; base < end; base += 16) {
        int je = base + eg;                              // pk padded by 16
        int s = (je < end) ? pk[je] : ZROW;              // ZROW gathers zeros
        uint4 r = inv[s * 4 + cs];
        const __half2* h2 = (const __half2*)&r;
        float2 f;
        f = __half22float2(h2[0]); acc[0] += f.x; acc[1] += f.y;
        f = __half22float2(h2[1]); acc[2] += f.x; acc[3] += f.y;
        f = __half22float2(h2[2]); acc[4] += f.x; acc[5] += f.y;
        f = __half22float2(h2[3]); acc[6] += f.x; acc[7] += f.y;
    }
#pragma unroll
    for (int m = 4; m <= 32; m <<= 1)
#pragma unroll
        for (int i = 0; i < 8; ++i) acc[i] += __shfl_xor(acc[i], m, 64);
    if (eg == 0) {
        uint4 sr = inv[w * 4 + cs];                      // self term
        const __half2* sh = (const __half2*)&sr;
        float2 f;
        f = __half22float2(sh[0]); acc[0] += f.x; acc[1] += f.y;
        f = __half22float2(sh[1]); acc[2] += f.x; acc[3] += f.y;
        f = __half22float2(sh[2]); acc[4] += f.x; acc[5] += f.y;
        f = __half22float2(sh[3]); acc[6] += f.x; acc[7] += f.y;
        float dw = dis[w];
        if (apply_relu) {
            float4 b0 = ((const float4*)bias)[2 * cs];
            float4 b1v = ((const float4*)bias)[2 * cs + 1];
            acc[0] = dw * fmaxf(dw * acc[0] + b0.x, 0.f);
            acc[1] = dw * fmaxf(dw * acc[1] + b0.y, 0.f);
            acc[2] = dw * fmaxf(dw * acc[2] + b0.z, 0.f);
            acc[3] = dw * fmaxf(dw * acc[3] + b0.w, 0.f);
            acc[4] = dw * fmaxf(dw * acc[4] + b1v.x, 0.f);
            acc[5] = dw * fmaxf(dw * acc[5] + b1v.y, 0.f);
            acc[6] = dw * fmaxf(dw * acc[6] + b1v.z, 0.f);
            acc[7] = dw * fmaxf(dw * acc[7] + b1v.w, 0.f);
        } else {
#pragma unroll
            for (int i = 0; i < 8; ++i) acc[i] *= dw;
        }
        __half2 o[4];
        o[0] = __floats2half2_rn(acc[0], acc[1]);
        o[1] = __floats2half2_rn(acc[2], acc[3]);
        o[2] = __floats2half2_rn(acc[4], acc[5]);
        o[3] = __floats2half2_rn(acc[6], acc[7]);
        ((uint4*)out)[w * 4 + cs] = *(const uint4*)o;
    }
}

// ---------------- out = agg2 @ [W_mu | W_logstd] + bias, 4x4 tiled ---------
__global__ __launch_bounds__(256) void k_mm2(const __half* __restrict__ a2lo,
                                             const __half* __restrict__ a2hi,
                                             const float* __restrict__ Wmu,
                                             const float* __restrict__ bmu,
                                             const float* __restrict__ Wls,
                                             const float* __restrict__ bls,
                                             float* __restrict__ out) {
    __shared__ float4 ws[64 * 16];      // [Wmu|Wls] combined [k][cq], 16 KB
    __shared__ float  xsT[64 * 64];     // agg2 tile transposed+swizzled, 16 KB
    int t = threadIdx.x;
    int n0 = blockIdx.x * 64;
    int lane = t & 63, wv_ = t >> 6;
    int ni = lane >> 2;
    int cq = ((lane & 3) << 2) + wv_;
    const float4* Wm4 = (const float4*)Wmu;
    const float4* Wl4 = (const float4*)Wls;
    const uint2* lo2 = (const uint2*)a2lo;
    const uint2* hi2 = (const uint2*)a2hi;
#pragma unroll
    for (int i = 0; i < 4; ++i) {
        int L = i * 256 + t;
        int k = L >> 4, c = L & 15;
        ws[L] = (c < 8) ? Wm4[k * 8 + c] : Wl4[k * 8 + (c - 8)];
        int n = L >> 4, q = L & 15;
        int ng = n0 + n; if (ng >= N_NODES) ng = N_NODES - 1;
        H4 hv;
        hv.u = (q < 8) ? lo2[ng * 8 + q] : hi2[ng * 8 + (q - 8)];
        float2 f0 = __half22float2(hv.h[0]), f1 = __half22float2(hv.h[1]);
        int fb = q * 256 + (((n >> 2) ^ q) << 2) + (n & 3);
        xsT[fb]       = f0.x;
        xsT[fb + 64]  = f0.y;
        xsT[fb + 128] = f1.x;
        xsT[fb + 192] = f1.y;
    }
    float4 b = (cq < 8) ? ((const float4*)bmu)[cq] : ((const float4*)bls)[cq - 8];
    float4 acc0 = b, acc1 = b, acc2 = b, acc3 = b;
    __syncthreads();
    const float4* xsT4 = (const float4*)xsT;
#pragma unroll 8
    for (int k = 0; k < 64; ++k) {
        float4 xv = xsT4[k * 16 + (ni ^ (k >> 2))];
        float4 wvv = ws[k * 16 + cq];
        acc0.x += xv.x * wvv.x; acc0.y += xv.x * wvv.y; acc0.z += xv.x * wvv.z; acc0.w += xv.x * wvv.w;
        acc1.x += xv.y * wvv.x; acc1.y += xv.y * wvv.y; acc1.z += xv.y * wvv.z; acc1.w += xv.y * wvv.w;
        acc2.x += xv.z * wvv.x; acc2.y += xv.z * wvv.y; acc2.z += xv.z * wvv.z; acc2.w += xv.z * wvv.w;
        acc3.x += xv.w * wvv.x; acc3.y += xv.w * wvv.y; acc3.z += xv.w * wvv.z; acc3.w += xv.w * wvv.w;
    }
    int nb = n0 + 4 * ni;
    if (nb < N_NODES) {
        float4* o4 = (float4*)out;
        long base_off = (cq < 8) ? 0 : (long)N_NODES * 8;
        int cq8 = cq & 7;
        o4[base_off + (long)(nb + 0) * 8 + cq8] = acc0;
        o4[base_off + (long)(nb + 1) * 8 + cq8] = acc1;
        o4[base_off + (long)(nb + 2) * 8 + cq8] = acc2;
        o4[base_off + (long)(nb + 3) * 8 + cq8] = acc3;
    }
}

extern "C" void kernel_launch(void* const* d_in, const int* in_sizes, int n_in,
                              void* d_out, int out_size, void* d_ws, size_t ws_size,
                              hipStream_t stream) {
    const float* x   = (const float*)d_in[0];
    const int*   ei  = (const int*)  d_in[1];
    const float* W1  = (const float*)d_in[2];
    const float* b1  = (const float*)d_in[3];
    const float* Wmu = (const float*)d_in[4];
    const float* bmu = (const float*)d_in[5];
    const float* Wls = (const float*)d_in[6];
    const float* bls = (const float*)d_in[7];
    float* out = (float*)d_out;

    // workspace layout (4-byte units)
    int*   cnt       = (int*)d_ws;                       // [0, 50176) + counter pad
    int*   total     = (int*)d_ws + 50200;               // scan base counter
    float* dis       = (float*)d_ws + 50432;             // 50000
    int*   row_start = (int*)d_ws + 100432;              // 50000
    int*   cur       = (int*)d_ws + 150432;              // 50000
    int*   pk        = (int*)d_ws + 200448;              // 800016 src indices
    __half* bufAlo   = (__half*)((int*)d_ws + 1000464);  // (N+1) x 32 half
    __half* bufAhi   = (__half*)((int*)d_ws + 1800480);
    __half* bufBlo   = (__half*)((int*)d_ws + 2600496);
    __half* bufBhi   = (__half*)((int*)d_ws + 3400512);
    __half* bufClo   = (__half*)((int*)d_ws + 4200528);  // N x 32 half
    __half* bufChi   = (__half*)((int*)d_ws + 5000528);

    hipMemsetAsync(d_ws, 0, 50432 * 4, stream);          // cnt + total
    k_hist    <<<3125, 256, 0, stream>>>(ei, cnt);
    k_scan    <<<NBLK, 256, 0, stream>>>(cnt, total, row_start, cur, dis, pk,
                   (unsigned*)(bufAlo + (size_t)ZROW * 32),
                   (unsigned*)(bufAhi + (size_t)ZROW * 32),
                   (unsigned*)(bufBlo + (size_t)ZROW * 32),
                   (unsigned*)(bufBhi + (size_t)ZROW * 32));
    k_scatter <<<3125 * 8, 256, 0, stream>>>(ei, cur, pk);
    k_mm1     <<<782, 256, 0, stream>>>(x, W1, dis, bufAlo, bufAhi);
    k_aggh    <<<12500, 256, 0, stream>>>(pk, row_start, cnt, dis, bufAlo, b1,      bufBlo, 1);
    k_aggh    <<<12500, 256, 0, stream>>>(pk, row_start, cnt, dis, bufAhi, b1 + 32, bufBhi, 1);
    k_aggh    <<<12500, 256, 0, stream>>>(pk, row_start, cnt, dis, bufBlo, nullptr, bufClo, 0);
    k_aggh    <<<12500, 256, 0, stream>>>(pk, row_start, cnt, dis, bufBhi, nullptr, bufChi, 0);
    k_mm2     <<<782, 256, 0, stream>>>(bufClo, bufChi, Wmu, bmu, Wls, bls, out);
}

// Round 9
// 231.673 us; speedup vs baseline: 1.2062x; 1.2062x over previous
//
#include <hip/hip_runtime.h>
#include <hip/hip_fp16.h>

#define N_NODES 50000
#define N_EDGES 800000
#define IN_CH 128
#define HID 64
#define OUT_CH 32
#define NBLK 196                 // ceil(50000/256)
#define PART_SZ 6250             // dst partition (XCD write affinity in scatter)
#define SLICE_SZ 12500           // src slice (gather locality): 4 slices x 1.6 MB
#define ZROW N_NODES             // all-zeros feature row (padding gathers)

union H4 { uint2 u; __half2 h[2]; };

// ---------------- histogram of (src-slice, dst) ----------------------------
__global__ __launch_bounds__(256) void k_hist(const int* __restrict__ ei, int* cnt) {
    int e = blockIdx.x * 256 + threadIdx.x;
    if (e >= N_EDGES) return;
    int s = ei[e], d = ei[N_EDGES + e];
    atomicAdd(&cnt[(s / SLICE_SZ) * 50176 + d], 1);
}

// ---------------- single-kernel scan: block scan + atomic base -------------
// Row ranges land in arbitrary block order (agg uses row_start/row_end only).
// Sub-segment cursors give each row the layout [slice0|slice1|slice2|slice3].
__global__ __launch_bounds__(256) void k_scan(const int* __restrict__ cnt, int* total,
                                              int* row_start, int* row_end, int* cur,
                                              float* dis, int* pk,
                                              unsigned* zA, unsigned* zB) {
    __shared__ int s[256];
    __shared__ int sbase;
    int t = threadIdx.x;
    int i = blockIdx.x * 256 + t;
    int c0 = cnt[i];
    int c1 = cnt[50176 + i];
    int c2 = cnt[2 * 50176 + i];
    int c3 = cnt[3 * 50176 + i];          // padded region zeroed by memset
    int v = c0 + c1 + c2 + c3;
    s[t] = v;
    __syncthreads();
    for (int off = 1; off < 256; off <<= 1) {
        int a = (t >= off) ? s[t - off] : 0;
        __syncthreads();
        s[t] += a;
        __syncthreads();
    }
    if (t == 255) sbase = atomicAdd(total, s[255]);
    __syncthreads();
    int excl = sbase + s[t] - v;
    if (i < N_NODES) {
        row_start[i] = excl;
        row_end[i]   = excl + v;
        cur[i]            = excl;
        cur[50000 + i]    = excl + c0;
        cur[100000 + i]   = excl + c0 + c1;
        cur[150000 + i]   = excl + c0 + c1 + c2;
        dis[i] = rsqrtf((float)(v + 1));  // self-loop included
    }
    if (blockIdx.x == 0) {
        if (t < 16) pk[N_EDGES + t] = ZROW;          // pad for 8-wide agg reads
        if (t < 32) { zA[t] = 0u; zB[t] = 0u; }      // 64-half zero rows
    }
}

// ---------------- scatter edges, XCD dst-partitioned, slice-ordered --------
__global__ __launch_bounds__(256) void k_scatter(const int* __restrict__ ei,
                                                 int* cur, int* __restrict__ pk) {
    int part = blockIdx.x & 7;
    int e = (blockIdx.x >> 3) * 256 + threadIdx.x;
    if (e >= N_EDGES) return;
    int d = ei[N_EDGES + e];
    if (d / PART_SZ != part) return;
    int s = ei[e];
    int pos = atomicAdd(&cur[(s / SLICE_SZ) * 50000 + d], 1);
    pk[pos] = s;
}

// ---------------- t1' = dis .* (x @ W1), register-tiled 4x4, half out ------
__global__ __launch_bounds__(256) void k_mm1(const float* __restrict__ x,
                                             const float* __restrict__ W1,
                                             const float* __restrict__ dis,
                                             __half* __restrict__ t1) {
    __shared__ float4 ws[64 * 16];      // W half-tile [k][cq], 16 KB
    __shared__ float  xsT[64 * 64];     // x half-tile, transposed+swizzled, 16 KB
    int t = threadIdx.x;
    int n0 = blockIdx.x * 64;
    int lane = t & 63, wv_ = t >> 6;
    int ni = lane >> 2;                 // node-quad 0..15
    int cq = ((lane & 3) << 2) + wv_;   // channel-quad 0..15
    const float4* W4 = (const float4*)W1;
    const float4* x4 = (const float4*)x;
    float4 acc0 = {0,0,0,0}, acc1 = acc0, acc2 = acc0, acc3 = acc0;
#pragma unroll
    for (int kt = 0; kt < 2; ++kt) {
        __syncthreads();
#pragma unroll
        for (int i = 0; i < 4; ++i) {
            int L = i * 256 + t;
            ws[L] = W4[kt * 1024 + L];
            int n = L >> 4, q = L & 15;
            int ng = n0 + n; if (ng >= N_NODES) ng = N_NODES - 1;
            float4 v = x4[ng * 32 + kt * 16 + q];
            int fb = q * 256 + (((n >> 2) ^ q) << 2) + (n & 3);
            xsT[fb]       = v.x;
            xsT[fb + 64]  = v.y;
            xsT[fb + 128] = v.z;
            xsT[fb + 192] = v.w;
        }
        __syncthreads();
        const float4* xsT4 = (const float4*)xsT;
#pragma unroll 8
        for (int k = 0; k < 64; ++k) {
            float4 xv = xsT4[k * 16 + (ni ^ (k >> 2))];
            float4 wvv = ws[k * 16 + cq];
            acc0.x += xv.x * wvv.x; acc0.y += xv.x * wvv.y; acc0.z += xv.x * wvv.z; acc0.w += xv.x * wvv.w;
            acc1.x += xv.y * wvv.x; acc1.y += xv.y * wvv.y; acc1.z += xv.y * wvv.z; acc1.w += xv.y * wvv.w;
            acc2.x += xv.z * wvv.x; acc2.y += xv.z * wvv.y; acc2.z += xv.z * wvv.z; acc2.w += xv.z * wvv.w;
            acc3.x += xv.w * wvv.x; acc3.y += xv.w * wvv.y; acc3.z += xv.w * wvv.z; acc3.w += xv.w * wvv.w;
        }
    }
    int nb = n0 + 4 * ni;
    if (nb < N_NODES) {
        float d0 = dis[nb], d1 = dis[nb + 1], d2 = dis[nb + 2], d3 = dis[nb + 3];
        uint2* o2 = (uint2*)t1;
        H4 v;
        v.h[0] = __floats2half2_rn(d0 * acc0.x, d0 * acc0.y);
        v.h[1] = __floats2half2_rn(d0 * acc0.z, d0 * acc0.w);
        o2[(nb + 0) * 16 + cq] = v.u;
        v.h[0] = __floats2half2_rn(d1 * acc1.x, d1 * acc1.y);
        v.h[1] = __floats2half2_rn(d1 * acc1.z, d1 * acc1.w);
        o2[(nb + 1) * 16 + cq] = v.u;
        v.h[0] = __floats2half2_rn(d2 * acc2.x, d2 * acc2.y);
        v.h[1] = __floats2half2_rn(d2 * acc2.z, d2 * acc2.w);
        o2[(nb + 2) * 16 + cq] = v.u;
        v.h[0] = __floats2half2_rn(d3 * acc3.x, d3 * acc3.y);
        v.h[1] = __floats2half2_rn(d3 * acc3.z, d3 * acc3.w);
        o2[(nb + 3) * 16 + cq] = v.u;
    }
}

// ---------------- aggregation: pure sum, one wave/node, 8 edges/instr ------
// acc = sum in[src] + in[w]   (in pre-scaled by dis on the write side)
// mode 1: out = half( dis[w] * relu(dis[w]*acc + bias) )
// mode 0: out = half( dis[w] * acc )
__global__ __launch_bounds__(256) void k_agg(const int* __restrict__ pk,
                                             const int* __restrict__ row_start,
                                             const int* __restrict__ row_end,
                                             const float* __restrict__ dis,
                                             const __half* __restrict__ in,
                                             const float* __restrict__ bias,
                                             __half* __restrict__ out,
                                             int apply_relu) {
    int w = (blockIdx.x * 256 + threadIdx.x) >> 6;
    if (w >= N_NODES) return;
    int lane = threadIdx.x & 63;
    int eg = lane >> 3, cs = lane & 7;
    int beg = row_start[w], end = row_end[w];
    const uint4* __restrict__ inv = (const uint4*)in;    // 8 uint4 per row
    float acc[8] = {0,0,0,0,0,0,0,0};
#pragma unroll 2
    for (int base = beg; base < end; base += 8) {
        int je = base + eg;
        int s = (je < end) ? pk[je] : ZROW;              // ZROW gathers zeros
        uint4 r = inv[s * 8 + cs];
        const __half2* h2 = (const __half2*)&r;
        float2 f;
        f = __half22float2(h2[0]); acc[0] += f.x; acc[1] += f.y;
        f = __half22float2(h2[1]); acc[2] += f.x; acc[3] += f.y;
        f = __half22float2(h2[2]); acc[4] += f.x; acc[5] += f.y;
        f = __half22float2(h2[3]); acc[6] += f.x; acc[7] += f.y;
    }
#pragma unroll
    for (int m = 8; m <= 32; m <<= 1)
#pragma unroll
        for (int i = 0; i < 8; ++i) acc[i] += __shfl_xor(acc[i], m, 64);
    if (eg == 0) {
        uint4 sr = inv[w * 8 + cs];                      // self term in[w]
        const __half2* sh = (const __half2*)&sr;
        float2 f;
        f = __half22float2(sh[0]); acc[0] += f.x; acc[1] += f.y;
        f = __half22float2(sh[1]); acc[2] += f.x; acc[3] += f.y;
        f = __half22float2(sh[2]); acc[4] += f.x; acc[5] += f.y;
        f = __half22float2(sh[3]); acc[6] += f.x; acc[7] += f.y;
        float dw = dis[w];
        if (apply_relu) {
            float4 b0 = ((const float4*)bias)[2 * cs];
            float4 b1v = ((const float4*)bias)[2 * cs + 1];
            acc[0] = dw * fmaxf(dw * acc[0] + b0.x, 0.f);
            acc[1] = dw * fmaxf(dw * acc[1] + b0.y, 0.f);
            acc[2] = dw * fmaxf(dw * acc[2] + b0.z, 0.f);
            acc[3] = dw * fmaxf(dw * acc[3] + b0.w, 0.f);
            acc[4] = dw * fmaxf(dw * acc[4] + b1v.x, 0.f);
            acc[5] = dw * fmaxf(dw * acc[5] + b1v.y, 0.f);
            acc[6] = dw * fmaxf(dw * acc[6] + b1v.z, 0.f);
            acc[7] = dw * fmaxf(dw * acc[7] + b1v.w, 0.f);
        } else {
#pragma unroll
            for (int i = 0; i < 8; ++i) acc[i] *= dw;
        }
        __half2 o[4];
        o[0] = __floats2half2_rn(acc[0], acc[1]);
        o[1] = __floats2half2_rn(acc[2], acc[3]);
        o[2] = __floats2half2_rn(acc[4], acc[5]);
        o[3] = __floats2half2_rn(acc[6], acc[7]);
        ((uint4*)out)[w * 8 + cs] = *(const uint4*)o;
    }
}

// ---------------- out = agg2 @ [W_mu | W_logstd] + bias, 4x4 tiled ---------
__global__ __launch_bounds__(256) void k_mm2(const __half* __restrict__ agg2,
                                             const float* __restrict__ Wmu,
                                             const float* __restrict__ bmu,
                                             const float* __restrict__ Wls,
                                             const float* __restrict__ bls,
                                             float* __restrict__ out) {
    __shared__ float4 ws[64 * 16];      // [Wmu|Wls] combined [k][cq], 16 KB
    __shared__ float  xsT[64 * 64];     // agg2 tile transposed+swizzled, 16 KB
    int t = threadIdx.x;
    int n0 = blockIdx.x * 64;
    int lane = t & 63, wv_ = t >> 6;
    int ni = lane >> 2;
    int cq = ((lane & 3) << 2) + wv_;
    const float4* Wm4 = (const float4*)Wmu;
    const float4* Wl4 = (const float4*)Wls;
    const uint2*  x2  = (const uint2*)agg2;          // 16 uint2 per 64-half row
#pragma unroll
    for (int i = 0; i < 4; ++i) {
        int L = i * 256 + t;
        int k = L >> 4, c = L & 15;
        ws[L] = (c < 8) ? Wm4[k * 8 + c] : Wl4[k * 8 + (c - 8)];
        int n = L >> 4, q = L & 15;
        int ng = n0 + n; if (ng >= N_NODES) ng = N_NODES - 1;
        H4 hv; hv.u = x2[ng * 16 + q];
        float2 f0 = __half22float2(hv.h[0]), f1 = __half22float2(hv.h[1]);
        int fb = q * 256 + (((n >> 2) ^ q) << 2) + (n & 3);
        xsT[fb]       = f0.x;
        xsT[fb + 64]  = f0.y;
        xsT[fb + 128] = f1.x;
        xsT[fb + 192] = f1.y;
    }
    float4 b = (cq < 8) ? ((const float4*)bmu)[cq] : ((const float4*)bls)[cq - 8];
    float4 acc0 = b, acc1 = b, acc2 = b, acc3 = b;
    __syncthreads();
    const float4* xsT4 = (const float4*)xsT;
#pragma unroll 8
    for (int k = 0; k < 64; ++k) {
        float4 xv = xsT4[k * 16 + (ni ^ (k >> 2))];
        float4 wvv = ws[k * 16 + cq];
        acc0.x += xv.x * wvv.x; acc0.y += xv.x * wvv.y; acc0.z += xv.x * wvv.z; acc0.w += xv.x * wvv.w;
        acc1.x += xv.y * wvv.x; acc1.y += xv.y * wvv.y; acc1.z += xv.y * wvv.z; acc1.w += xv.y * wvv.w;
        acc2.x += xv.z * wvv.x; acc2.y += xv.z * wvv.y; acc2.z += xv.z * wvv.z; acc2.w += xv.z * wvv.w;
        acc3.x += xv.w * wvv.x; acc3.y += xv.w * wvv.y; acc3.z += xv.w * wvv.z; acc3.w += xv.w * wvv.w;
    }
    int nb = n0 + 4 * ni;
    if (nb < N_NODES) {
        float4* o4 = (float4*)out;
        long base_off = (cq < 8) ? 0 : (long)N_NODES * 8;
        int cq8 = cq & 7;
        o4[base_off + (long)(nb + 0) * 8 + cq8] = acc0;
        o4[base_off + (long)(nb + 1) * 8 + cq8] = acc1;
        o4[base_off + (long)(nb + 2) * 8 + cq8] = acc2;
        o4[base_off + (long)(nb + 3) * 8 + cq8] = acc3;
    }
}

extern "C" void kernel_launch(void* const* d_in, const int* in_sizes, int n_in,
                              void* d_out, int out_size, void* d_ws, size_t ws_size,
                              hipStream_t stream) {
    const float* x   = (const float*)d_in[0];
    const int*   ei  = (const int*)  d_in[1];
    const float* W1  = (const float*)d_in[2];
    const float* b1  = (const float*)d_in[3];
    const float* Wmu = (const float*)d_in[4];
    const float* bmu = (const float*)d_in[5];
    const float* Wls = (const float*)d_in[6];
    const float* bls = (const float*)d_in[7];
    float* out = (float*)d_out;

    // workspace layout (4-byte units)
    int*   cnt       = (int*)d_ws;                       // 4 x 50176 slice hists
    int*   total     = (int*)d_ws + 200704;              // scan base (pad to 200768)
    float* dis       = (float*)d_ws + 200768;            // 50000
    int*   row_start = (int*)d_ws + 250768;              // 50000
    int*   row_end   = (int*)d_ws + 300768;              // 50000
    int*   cur       = (int*)d_ws + 350768;              // 4 x 50000 cursors
    int*   pk        = (int*)d_ws + 550768;              // 800016 src indices
    __half* bufA     = (__half*)((int*)d_ws + 1350784);  // (N+1) x 64 half  t1'
    __half* bufB     = (__half*)((int*)d_ws + 2950816);  // (N+1) x 64 half  h'
    __half* bufC     = (__half*)((int*)d_ws + 4550848);  // N x 64 half      agg2'

    hipMemsetAsync(d_ws, 0, 803072, stream);             // cnt slices + total
    k_hist    <<<3125, 256, 0, stream>>>(ei, cnt);
    k_scan    <<<NBLK, 256, 0, stream>>>(cnt, total, row_start, row_end, cur, dis, pk,
                   (unsigned*)(bufA + (size_t)ZROW * HID),
                   (unsigned*)(bufB + (size_t)ZROW * HID));
    k_scatter <<<3125 * 8, 256, 0, stream>>>(ei, cur, pk);
    k_mm1     <<<782, 256, 0, stream>>>(x, W1, dis, bufA);
    k_agg     <<<12500, 256, 0, stream>>>(pk, row_start, row_end, dis, bufA, b1, bufB, 1);
    k_agg     <<<12500, 256, 0, stream>>>(pk, row_start, row_end, dis, bufB, nullptr, bufC, 0);
    k_mm2     <<<782, 256, 0, stream>>>(bufC, Wmu, bmu, Wls, bls, out);
}